// Round 1
// baseline (90.462 us; speedup 1.0000x reference)
//
#include <hip/hip_runtime.h>
#include <math.h>

#define NB 32        // n_basis
#define ED 256       // embed_dim
#define BB 8         // batch
#define XX 4096      // grid points
#define AA 64        // atoms
#define EPS 1e-4f
#define LOG2E 1.44269504088896340736f
#define LN2   0.69314718055994530942f
#define PI_F  3.14159265358979323846f

// -------- Kernel 1: partial pooled sums --------
// grid: BB*XC blocks, 256 threads = 4 waves; wave w owns all 64 'a' lanes,
// iterates over its x-slice. part layout: [B][A][XC][NB]
template <int XC>
__global__ __launch_bounds__(256) void k_pool(
    const float* __restrict__ wrho,    // [B][X]
    const float* __restrict__ dist,    // [B][X][A]
    const float* __restrict__ gammas,  // [NB]
    float* __restrict__ part)          // [B][A][XC][NB]
{
    constexpr int XPB = XX / XC;       // x per block
    constexpr int XPW = XPB / 4;       // x per wave
    const int blk = blockIdx.x;
    const int b = blk / XC;
    const int c = blk % XC;
    const int t = threadIdx.x;
    const int a = t & 63;
    const int w = t >> 6;              // wave id 0..3

    // uniform per-s constants: -gamma_s * log2(e), held in SGPRs
    float mg2[NB];
#pragma unroll
    for (int s = 0; s < NB; ++s) {
        float g = gammas[s];
        float v = -g * LOG2E;
        mg2[s] = __uint_as_float(__builtin_amdgcn_readfirstlane(__float_as_uint(v)));
    }

    float acc[NB];
#pragma unroll
    for (int s = 0; s < NB; ++s) acc[s] = 0.f;

    const int x0 = c * XPB + w * XPW;
    const float* dptr = dist + ((size_t)b * XX + x0) * AA + a;
    const float* wptr = wrho + (size_t)b * XX + x0;

    for (int i = 0; i < XPW; ++i) {
        float d  = dptr[(size_t)i * AA];            // 256B coalesced per wave
        float wv = __uint_as_float(__builtin_amdgcn_readfirstlane(
                       __float_as_uint(wptr[i])));  // wave-uniform
        float d2 = d * d;
#pragma unroll
        for (int s = 0; s < NB; ++s) {
            float e = exp2f(mg2[s] * d2);           // v_exp_f32
            acc[s] = fmaf(wv, e, acc[s]);
        }
    }

    // cross-wave reduce via LDS (pad +1 float: [a][s] writes would be 32-way conflicted)
    __shared__ float red[4][AA][NB + 1];
#pragma unroll
    for (int s = 0; s < NB; ++s) red[w][a][s] = acc[s];
    __syncthreads();

    for (int p = t; p < AA * NB; p += 256) {
        int pa = p >> 5, ps = p & 31;
        float v = red[0][pa][ps] + red[1][pa][ps] + red[2][pa][ps] + red[3][pa][ps];
        part[(((size_t)b * AA + pa) * XC + c) * NB + ps] = v;
    }
}

// -------- Kernel 2: reduce chunks, phi = log(norm*S + eps), lift by W --------
// grid: BB*AA blocks, 256 threads (one per embed dim)
template <int XC>
__global__ __launch_bounds__(256) void k_lift(
    const float* __restrict__ part,    // [B][A][XC][NB]
    const float* __restrict__ gammas,  // [NB]
    const float* __restrict__ W,       // [ED][NB]
    float* __restrict__ out)           // [B][A][ED]
{
    const int blk = blockIdx.x;
    const int b = blk >> 6;
    const int a = blk & 63;
    const int t = threadIdx.x;

    __shared__ float phi[NB];
    __shared__ float red[8][NB];

    const float* p = part + (((size_t)b * AA + a) * XC) * NB;
    {
        int s = t & 31, g = t >> 5;    // 8 groups of 32
        float sum = 0.f;
        for (int c = g; c < XC; c += 8) sum += p[c * NB + s];
        red[g][s] = sum;
    }
    __syncthreads();
    if (t < NB) {
        float sum = 0.f;
#pragma unroll
        for (int g = 0; g < 8; ++g) sum += red[g][t];
        float gm = gammas[t];
        // norms = (pi/gamma)^1.5 via exp2/log2
        float norm = exp2f(1.5f * log2f(PI_F / gm));
        phi[t] = LN2 * log2f(fmaf(norm, sum, EPS));
    }
    __syncthreads();

    // out[b][a][t] = sum_s phi[s] * W[t][s]
    const float4* Wv = (const float4*)(W + (size_t)t * NB);
    float r = 0.f;
#pragma unroll
    for (int q = 0; q < NB / 4; ++q) {
        float4 wv = Wv[q];
        r = fmaf(wv.x, phi[q * 4 + 0], r);
        r = fmaf(wv.y, phi[q * 4 + 1], r);
        r = fmaf(wv.z, phi[q * 4 + 2], r);
        r = fmaf(wv.w, phi[q * 4 + 3], r);
    }
    out[((size_t)b * AA + a) * ED + t] = r;
}

extern "C" void kernel_launch(void* const* d_in, const int* in_sizes, int n_in,
                              void* d_out, int out_size, void* d_ws, size_t ws_size,
                              hipStream_t stream) {
    const float* wrho   = (const float*)d_in[0];
    const float* dist   = (const float*)d_in[1];
    const float* gammas = (const float*)d_in[2];
    const float* W      = (const float*)d_in[3];
    float* out  = (float*)d_out;
    float* part = (float*)d_ws;

    const size_t need64 = (size_t)BB * AA * 64 * NB * sizeof(float);  // 4 MB
    const size_t need16 = (size_t)BB * AA * 16 * NB * sizeof(float);  // 1 MB

    if (ws_size >= need64) {
        k_pool<64><<<BB * 64, 256, 0, stream>>>(wrho, dist, gammas, part);
        k_lift<64><<<BB * AA, 256, 0, stream>>>(part, gammas, W, out);
    } else if (ws_size >= need16) {
        k_pool<16><<<BB * 16, 256, 0, stream>>>(wrho, dist, gammas, part);
        k_lift<16><<<BB * AA, 256, 0, stream>>>(part, gammas, W, out);
    } else {
        k_pool<4><<<BB * 4, 256, 0, stream>>>(wrho, dist, gammas, part);
        k_lift<4><<<BB * AA, 256, 0, stream>>>(part, gammas, W, out);
    }
}

// Round 2
// 80.746 us; speedup vs baseline: 1.1203x; 1.1203x over previous
//
#include <hip/hip_runtime.h>
#include <math.h>

#define NB 32        // n_basis
#define ED 256       // embed_dim
#define BB 8         // batch
#define XX 4096      // grid points
#define AA 64        // atoms
#define EPS 1e-4f
#define LOG2E 1.44269504088896340736f
#define LN2   0.69314718055994530942f
#define PI_F  3.14159265358979323846f

// -------- Kernel 1: partial pooled sums --------
// grid: BB*XC blocks, 256 threads = 4 waves; wave w owns all 64 'a' lanes,
// iterates over its x-slice. part layout: [B][A][XC][NB]
// Trans-pipe-bound: 32 v_exp_f32 per (x,a) element -> 256 cyc/x per wave;
// 16-deep load prefetch hides HBM latency under the exp burst.
template <int XC>
__global__ __launch_bounds__(256) void k_pool(
    const float* __restrict__ wrho,    // [B][X]
    const float* __restrict__ dist,    // [B][X][A]
    const float* __restrict__ gammas,  // [NB]
    float* __restrict__ part)          // [B][A][XC][NB]
{
    constexpr int XPB = XX / XC;       // x per block
    constexpr int XPW = XPB / 4;       // x per wave
    static_assert(XPW % 16 == 0, "prefetch depth");
    const int blk = blockIdx.x;
    const int b = blk / XC;
    const int c = blk % XC;
    const int t = threadIdx.x;
    const int a = t & 63;
    const int w = t >> 6;              // wave id 0..3

    // uniform per-s constants: -gamma_s * log2(e), forced into SGPRs
    float mg2[NB];
#pragma unroll
    for (int s = 0; s < NB; ++s) {
        float g = gammas[s];
        float v = -g * LOG2E;
        mg2[s] = __uint_as_float(__builtin_amdgcn_readfirstlane(__float_as_uint(v)));
    }

    float acc[NB];
#pragma unroll
    for (int s = 0; s < NB; ++s) acc[s] = 0.f;

    const int x0 = c * XPB + w * XPW;
    const float* dptr = dist + ((size_t)b * XX + x0) * AA + a;
    const float* wptr = wrho + (size_t)b * XX + x0;

    for (int i0 = 0; i0 < XPW; i0 += 16) {
        // prefetch: issue all 32 loads, then one wait, then pure compute
        float dv[16], wq[16];
#pragma unroll
        for (int j = 0; j < 16; ++j) {
            dv[j] = dptr[(size_t)(i0 + j) * AA];   // 256B coalesced per wave
            wq[j] = wptr[i0 + j];                  // same-addr broadcast load
        }
#pragma unroll
        for (int j = 0; j < 16; ++j) {
            float d2 = dv[j] * dv[j];
            float wv = wq[j];
#pragma unroll
            for (int s = 0; s < NB; ++s) {
                float e = __builtin_amdgcn_exp2f(mg2[s] * d2);  // raw v_exp_f32
                acc[s] = fmaf(wv, e, acc[s]);
            }
        }
    }

    // cross-wave reduce via LDS (pad +1 float: [a][s] writes would be 32-way conflicted)
    __shared__ float red[4][AA][NB + 1];
#pragma unroll
    for (int s = 0; s < NB; ++s) red[w][a][s] = acc[s];
    __syncthreads();

    for (int p = t; p < AA * NB; p += 256) {
        int pa = p >> 5, ps = p & 31;
        float v = red[0][pa][ps] + red[1][pa][ps] + red[2][pa][ps] + red[3][pa][ps];
        part[(((size_t)b * AA + pa) * XC + c) * NB + ps] = v;
    }
}

// -------- Kernel 2: reduce chunks, phi = log(norm*S + eps), lift by W --------
// grid: BB*AA blocks, 256 threads (one per embed dim)
template <int XC>
__global__ __launch_bounds__(256) void k_lift(
    const float* __restrict__ part,    // [B][A][XC][NB]
    const float* __restrict__ gammas,  // [NB]
    const float* __restrict__ W,       // [ED][NB]
    float* __restrict__ out)           // [B][A][ED]
{
    const int blk = blockIdx.x;
    const int b = blk >> 6;
    const int a = blk & 63;
    const int t = threadIdx.x;

    __shared__ float phi[NB];
    __shared__ float red[8][NB];

    const float* p = part + (((size_t)b * AA + a) * XC) * NB;
    {
        int s = t & 31, g = t >> 5;    // 8 groups of 32
        float sum = 0.f;
        for (int c = g; c < XC; c += 8) sum += p[c * NB + s];
        red[g][s] = sum;
    }
    __syncthreads();
    if (t < NB) {
        float sum = 0.f;
#pragma unroll
        for (int g = 0; g < 8; ++g) sum += red[g][t];
        float gm = gammas[t];
        // norms = (pi/gamma)^1.5 via exp2/log2
        float norm = exp2f(1.5f * log2f(PI_F / gm));
        phi[t] = LN2 * log2f(fmaf(norm, sum, EPS));
    }
    __syncthreads();

    // out[b][a][t] = sum_s phi[s] * W[t][s]
    const float4* Wv = (const float4*)(W + (size_t)t * NB);
    float r = 0.f;
#pragma unroll
    for (int q = 0; q < NB / 4; ++q) {
        float4 wv = Wv[q];
        r = fmaf(wv.x, phi[q * 4 + 0], r);
        r = fmaf(wv.y, phi[q * 4 + 1], r);
        r = fmaf(wv.z, phi[q * 4 + 2], r);
        r = fmaf(wv.w, phi[q * 4 + 3], r);
    }
    out[((size_t)b * AA + a) * ED + t] = r;
}

extern "C" void kernel_launch(void* const* d_in, const int* in_sizes, int n_in,
                              void* d_out, int out_size, void* d_ws, size_t ws_size,
                              hipStream_t stream) {
    const float* wrho   = (const float*)d_in[0];
    const float* dist   = (const float*)d_in[1];
    const float* gammas = (const float*)d_in[2];
    const float* W      = (const float*)d_in[3];
    float* out  = (float*)d_out;
    float* part = (float*)d_ws;

    const size_t need64 = (size_t)BB * AA * 64 * NB * sizeof(float);  // 4 MB
    const size_t need16 = (size_t)BB * AA * 16 * NB * sizeof(float);  // 1 MB

    if (ws_size >= need64) {
        k_pool<64><<<BB * 64, 256, 0, stream>>>(wrho, dist, gammas, part);
        k_lift<64><<<BB * AA, 256, 0, stream>>>(part, gammas, W, out);
    } else if (ws_size >= need16) {
        k_pool<16><<<BB * 16, 256, 0, stream>>>(wrho, dist, gammas, part);
        k_lift<16><<<BB * AA, 256, 0, stream>>>(part, gammas, W, out);
    } else {
        k_pool<4><<<BB * 4, 256, 0, stream>>>(wrho, dist, gammas, part);
        k_lift<4><<<BB * AA, 256, 0, stream>>>(part, gammas, W, out);
    }
}